// Round 1
// 215.048 us; speedup vs baseline: 1.0088x; 1.0088x over previous
//
#include <hip/hip_runtime.h>
#include <type_traits>

// SOC scan:  SOC[b,t] = SOC_init(b) + sum_{k<=t} g[k],  g[0]=0,
//   g[t]  = (ts[t]-ts[t-1]) * f[t-1]
//   f[t]  = (c1 + c2*softplus(I*w1e0 + Te*w1e1 + b1e)) * I[t]
//   c1 = coef*(1+b2e), c2 = coef*w2e, coef = eta0/(3600*Q)
//
// R8: rocprof decomposition: timed graph = 2x 512MiB poison fills (~157us,
// harness) + our kernel (~60us vs 26.6us HBM floor for 160MiB). In-flight
// bytes are fine (128KB/CU ring), so the remaining 2.2x is the shuffle-scan
// serial chain: 11 ds_bpermute per 64-elem chunk x 32 chunks = 352 bpermutes
// and ~600-1000cy of dependent LDS round-trips per chunk stalling in-order
// issue. Fix: K=4 thread-serial sub-scan (thread owns 4 consecutive
// timesteps = one aligned 64B line). One wave scan per 256 elements ->
// 88 bpermutes/wave, chain /4, and fully-coalesced float4 stores.

static __device__ __forceinline__ float bf2f(unsigned int u) {
    union { unsigned int i; float f; } v;
    v.i = u << 16;
    return v.f;
}
static __device__ __forceinline__ unsigned short f2bf(float f) {
    union { unsigned int i; float f; } v;
    v.f = f;
    unsigned int x = v.i;
    return (unsigned short)((x + 0x7fffu + ((x >> 16) & 1u)) >> 16);  // RNE
}
static __device__ __forceinline__ float sp_fast(float x) {
    return __logf(1.f + __expf(x));   // v_exp_f32 / v_log_f32, |x| << 88
}

struct F4 { float ts, I, Te, U; };
static __device__ __forceinline__ F4 dec(ushort4 x) {
    return {bf2f(x.x), bf2f(x.y), bf2f(x.z), bf2f(x.w)};
}
static __device__ __forceinline__ F4 dec(float4 x) {
    return {x.x, x.y, x.z, x.w};
}

template <bool BF16>
static __device__ __forceinline__ float ld(const void* p, int i) {
    return BF16 ? bf2f(((const unsigned short*)p)[i]) : ((const float*)p)[i];
}

constexpr int BLOCK = 256;

// ---------------- main path: f32, T == NCH*1024, K=4 thread-serial --------
// chunk = 256 timesteps (64 lanes x 4 consecutive); NCH chunks per wave.
template <int NCH>
static __device__ void scan_k4(
    const float* __restrict__ X, const float* __restrict__ SC,
    const float* __restrict__ W1i, const float* __restrict__ b1i,
    const float* __restrict__ W2i, const float* __restrict__ b2i,
    const float* __restrict__ W1e, const float* __restrict__ b1e,
    const float* __restrict__ W2e, const float* __restrict__ b2e,
    float* __restrict__ outv, float* s_wtot, float* s_init)
{
    constexpr int SPAN = NCH * 256;       // timesteps per wave
    constexpr int T    = SPAN * 4;

    const int b    = blockIdx.x;
    const int tid  = threadIdx.x;
    const int lane = tid & 63;
    const int wave = tid >> 6;
    const int ws   = wave * SPAN;

    const float Q    = SC[b * 4 + 0];
    const float eta0 = SC[b * 4 + 1];
    const float R    = SC[b * 4 + 2];
    const float S3   = SC[b * 4 + 3];
    const float w1e0 = W1e[0];
    const float w1e1 = W1e[1];
    const float vb1e = b1e[0];
    const float coef = eta0 / (3600.f * Q);
    const float c2   = coef * W2e[0];
    const float c1   = coef * (1.f + b2e[0]);

    const float4* Xrow = (const float4*)X + (size_t)b * T;

    // ring: 2 chunks (8 x float4 per thread) in flight before any use
    float4 ring[8];
    #pragma unroll
    for (int c = 0; c < 2; ++c)
        #pragma unroll
        for (int j = 0; j < 4; ++j)
            ring[c * 4 + j] = Xrow[ws + c * 256 + lane * 4 + j];

    // wave-predecessor carry (one broadcast load; overlaps ring fill)
    float ts_c, f_c;
    if (wave > 0) {
        const float4 vp = Xrow[ws - 1];
        const float hp = sp_fast(fmaf(vp.y, w1e0, fmaf(vp.z, w1e1, vb1e)));
        f_c  = fmaf(c2, hp, c1) * vp.y;
        ts_c = vp.x;
    } else {
        const float4 v0 = Xrow[0];
        ts_c = v0.x;                     // makes g[0] = (ts0-ts0)*0 = 0
        f_c  = 0.f;
        const float pre = fmaf(v0.y, W1i[0],
                          fmaf(v0.z, W1i[1],
                          fmaf(v0.w, W1i[2],
                          fmaf(R, W1i[3], b1i[0]))));
        const float h0 = sp_fast(pre);
        if (lane == 0)
            *s_init = S3 * (1.f + fmaf(h0, W2i[0], b2i[0]));
    }

    float vals[NCH * 4];
    float carry = 0.f;
    #pragma unroll
    for (int c = 0; c < NCH; ++c) {
        const int s = (c & 1) * 4;
        const float4 v0 = ring[s + 0];
        const float4 v1 = ring[s + 1];
        const float4 v2 = ring[s + 2];
        const float4 v3 = ring[s + 3];
        if (c + 2 < NCH) {               // refill: keeps ~8 loads outstanding
            #pragma unroll
            for (int j = 0; j < 4; ++j)
                ring[s + j] = Xrow[ws + (c + 2) * 256 + lane * 4 + j];
        }

        const float f0 = fmaf(c2, sp_fast(fmaf(v0.y, w1e0, fmaf(v0.z, w1e1, vb1e))), c1) * v0.y;
        const float f1 = fmaf(c2, sp_fast(fmaf(v1.y, w1e0, fmaf(v1.z, w1e1, vb1e))), c1) * v1.y;
        const float f2 = fmaf(c2, sp_fast(fmaf(v2.y, w1e0, fmaf(v2.z, w1e1, vb1e))), c1) * v2.y;
        const float f3 = fmaf(c2, sp_fast(fmaf(v3.y, w1e0, fmaf(v3.z, w1e1, vb1e))), c1) * v3.y;

        // predecessor of this thread's first element = lane-1's last element
        float pts = __shfl_up(v3.x, 1, 64);
        float pf  = __shfl_up(f3,   1, 64);
        if (lane == 0) { pts = ts_c; pf = f_c; }

        // thread-local inclusive prefix over 4 consecutive timesteps
        const float g0 = (v0.x - pts) * pf;
        const float g1 = fmaf(v1.x - v0.x, f0, g0);
        const float g2 = fmaf(v2.x - v1.x, f1, g1);
        const float g3 = fmaf(v3.x - v2.x, f2, g2);

        // wave inclusive scan over thread totals (the only shuffle chain)
        float S = g3;
        #pragma unroll
        for (int d = 1; d < 64; d <<= 1) {
            const float u = __shfl_up(S, d, 64);
            if (lane >= d) S += u;
        }
        const float tb = carry + (S - g3);   // exclusive prefix for thread
        vals[c * 4 + 0] = g0 + tb;
        vals[c * 4 + 1] = g1 + tb;
        vals[c * 4 + 2] = g2 + tb;
        vals[c * 4 + 3] = g3 + tb;

        carry += __shfl(S, 63, 64);          // serial carry (only true dep)
        ts_c   = __shfl(v3.x, 63, 64);
        f_c    = __shfl(f3, 63, 64);
    }
    if (lane == 0) s_wtot[wave] = carry;
    __syncthreads();                         // the ONLY barrier

    float base = *s_init;
    #pragma unroll
    for (int w = 0; w < 3; ++w)
        if (w < wave) base += s_wtot[w];

    // fully-coalesced float4 stores: thread owns 4 consecutive outputs
    float4* orow = (float4*)(outv + (size_t)b * T);
    #pragma unroll
    for (int c = 0; c < NCH; ++c) {
        float4 o;
        o.x = vals[c * 4 + 0] + base;
        o.y = vals[c * 4 + 1] + base;
        o.z = vals[c * 4 + 2] + base;
        o.w = vals[c * 4 + 3] + base;
        orow[wave * (SPAN / 4) + c * 64 + lane] = o;
    }
}

__global__ __launch_bounds__(BLOCK, 4) void socnet_reg(
    const void* __restrict__ X, const void* __restrict__ SC,
    const void* __restrict__ W1i, const void* __restrict__ b1i,
    const void* __restrict__ W2i, const void* __restrict__ b2i,
    const void* __restrict__ W1e, const void* __restrict__ b1e,
    const void* __restrict__ W2e, const void* __restrict__ b2e,
    void* __restrict__ out)
{
    __shared__ float s_wtot[4];
    __shared__ float s_init;
    scan_k4<8>((const float*)X, (const float*)SC,
               (const float*)W1i, (const float*)b1i,
               (const float*)W2i, (const float*)b2i,
               (const float*)W1e, (const float*)b1e,
               (const float*)W2e, (const float*)b2e,
               (float*)out, s_wtot, &s_init);
}

// ---------------- fallback (bf16 input or odd T): serial-carry, correct ----
template <bool BF16>
static __device__ void scan_serial(
    const void* __restrict__ Xv, const void* __restrict__ SCv,
    const void* __restrict__ W1i, const void* __restrict__ b1i,
    const void* __restrict__ W2i, const void* __restrict__ b2i,
    const void* __restrict__ W1e, const void* __restrict__ b1e,
    const void* __restrict__ W2e, const void* __restrict__ b2e,
    void* __restrict__ outv, int T,
    float* s_wts, float* s_wf, float* s_wsum, float* s_carr)
{
    using XVec = typename std::conditional<BF16, ushort4, float4>::type;
    const int b = blockIdx.x, tid = threadIdx.x;
    const int lane = tid & 63, wave = tid >> 6;
    const int ntile = (T + BLOCK - 1) / BLOCK;

    const float Q    = ld<BF16>(SCv, b * 4 + 0);
    const float eta0 = ld<BF16>(SCv, b * 4 + 1);
    const float R    = ld<BF16>(SCv, b * 4 + 2);
    const float S3   = ld<BF16>(SCv, b * 4 + 3);
    const float w1e0 = ld<BF16>(W1e, 0);
    const float w1e1 = ld<BF16>(W1e, 1);
    const float vb1e = ld<BF16>(b1e, 0);
    const float coef = eta0 / (3600.f * Q);
    const float c2   = coef * ld<BF16>(W2e, 0);
    const float c1   = coef * (1.f + ld<BF16>(b2e, 0));

    const XVec* Xrow = (const XVec*)Xv + (size_t)b * T;

    for (int tile = 0; tile < ntile; ++tile) {
        const int t = tile * BLOCK + tid;
        const bool act = t < T;
        F4 v = {0.f, 0.f, 0.f, 0.f};
        if (act) v = dec(Xrow[t]);
        const float f = fmaf(c2, sp_fast(fmaf(v.I, w1e0, fmaf(v.Te, w1e1, vb1e))), c1) * v.I;

        float pts = __shfl_up(v.ts, 1, 64);
        float pf  = __shfl_up(f, 1, 64);

        __syncthreads();
        if (lane == 63) { s_wts[wave] = v.ts; s_wf[wave] = f; }
        if (tile == 0 && tid == 0) {
            const float pre = fmaf(v.I, ld<BF16>(W1i, 0),
                              fmaf(v.Te, ld<BF16>(W1i, 1),
                              fmaf(v.U, ld<BF16>(W1i, 2),
                              fmaf(R, ld<BF16>(W1i, 3), ld<BF16>(b1i, 0)))));
            s_carr[0] = S3 * (1.f + fmaf(sp_fast(pre), ld<BF16>(W2i, 0), ld<BF16>(b2i, 0)));
        }
        __syncthreads();
        if (lane == 0) {
            if (wave == 0) { if (tile > 0) { pts = s_carr[1]; pf = s_carr[2]; } }
            else { pts = s_wts[wave - 1]; pf = s_wf[wave - 1]; }
        }
        float g = (t == 0 || !act) ? 0.f : (v.ts - pts) * pf;
        #pragma unroll
        for (int d = 1; d < 64; d <<= 1) {
            const float u = __shfl_up(g, d, 64);
            if (lane >= d) g += u;
        }
        if (lane == 63) s_wsum[wave] = g;
        __syncthreads();
        float soc = s_carr[0];
        #pragma unroll
        for (int w = 0; w < 3; ++w) if (w < wave) soc += s_wsum[w];
        soc += g;
        if (act) {
            if (BF16) ((unsigned short*)outv)[(size_t)b * T + t] = f2bf(soc);
            else      ((float*)outv)[(size_t)b * T + t] = soc;
        }
        __syncthreads();
        if (tid == BLOCK - 1) { s_carr[0] = soc; s_carr[1] = v.ts; s_carr[2] = f; }
    }
}

__global__ __launch_bounds__(BLOCK) void socnet_serial_k(
    const void* __restrict__ X, const void* __restrict__ SC,
    const void* __restrict__ W1i, const void* __restrict__ b1i,
    const void* __restrict__ W2i, const void* __restrict__ b2i,
    const void* __restrict__ W1e, const void* __restrict__ b1e,
    const void* __restrict__ W2e, const void* __restrict__ b2e,
    void* __restrict__ out, int T)
{
    __shared__ float s_wts[4], s_wf[4], s_wsum[4], s_carr[3];
    const unsigned int* scw = (const unsigned int*)SC;
    const float l0 = bf2f(scw[0] & 0xFFFFu), l1 = bf2f(scw[1] & 0xFFFFu);
    const float l2 = bf2f(scw[2] & 0xFFFFu), l3 = bf2f(scw[3] & 0xFFFFu);
    const bool isbf =
        (l0 >= 0.45f && l0 <= 1.55f) && (l1 >= 0.45f && l1 <= 1.55f) &&
        (l2 >= 0.45f && l2 <= 1.55f) && (l3 >= 0.45f && l3 <= 1.55f);
    if (isbf) scan_serial<true >(X, SC, W1i, b1i, W2i, b2i, W1e, b1e, W2e, b2e,
                                 out, T, s_wts, s_wf, s_wsum, s_carr);
    else      scan_serial<false>(X, SC, W1i, b1i, W2i, b2i, W1e, b1e, W2e, b2e,
                                 out, T, s_wts, s_wf, s_wsum, s_carr);
}

extern "C" void kernel_launch(void* const* d_in, const int* in_sizes, int n_in,
                              void* d_out, int out_size, void* d_ws, size_t ws_size,
                              hipStream_t stream) {
    const int B = in_sizes[1] / 4;        // 1024
    const int T = in_sizes[0] / (B * 4);  // 8192

    // dtype check on host is impossible (no sync) — but round 2 resolved f32.
    // The f32 register path handles T==8192; anything else -> serial fallback
    // (which self-detects dtype on device).
    if (T == 8192) {
        socnet_reg<<<dim3(B), dim3(BLOCK), 0, stream>>>(
            d_in[0], d_in[1], d_in[2], d_in[3], d_in[4], d_in[5],
            d_in[6], d_in[7], d_in[8], d_in[9], d_out);
    } else {
        socnet_serial_k<<<dim3(B), dim3(BLOCK), 0, stream>>>(
            d_in[0], d_in[1], d_in[2], d_in[3], d_in[4], d_in[5],
            d_in[6], d_in[7], d_in[8], d_in[9], d_out, T);
    }
}